// Round 1
// baseline (247.384 us; speedup 1.0000x reference)
//
#include <hip/hip_runtime.h>

#define TPB 256

// ---------------- degree / normalization ----------------
__global__ void init_deg(float* deg, int n) {
    int i = blockIdx.x * blockDim.x + threadIdx.x;
    if (i < n) deg[i] = 1.0f;   // self loop contributes 1
}

__global__ void count_deg(const int* __restrict__ dst, float* deg, int e) {
    int i = blockIdx.x * blockDim.x + threadIdx.x;
    if (i < e) atomicAdd(&deg[dst[i]], 1.0f);
}

__global__ void deg_to_dinv(float* deg, int n) {
    int i = blockIdx.x * blockDim.x + threadIdx.x;
    if (i < n) {
        float d = deg[i];
        deg[i] = d > 0.0f ? rsqrtf(d) : 0.0f;
    }
}

// ---------------- small dense matmul: out[n,COUT] = in[n,CIN] @ W[CIN,COUT] (+b, relu) ----------------
template<int CIN, int COUT, bool BIAS, bool RELU>
__global__ void mm_kernel(const float* __restrict__ in, const float* __restrict__ W,
                          const float* __restrict__ b, float* __restrict__ out, int n) {
    __shared__ float Wl[CIN * COUT];
    for (int t = threadIdx.x; t < CIN * COUT; t += blockDim.x) Wl[t] = W[t];
    __syncthreads();
    int t = blockIdx.x * blockDim.x + threadIdx.x;
    int i = t / COUT, j = t - i * COUT;
    if (i >= n) return;
    float s = BIAS ? b[j] : 0.0f;
#pragma unroll
    for (int k = 0; k < CIN; ++k) s = fmaf(in[(size_t)i * CIN + k], Wl[k * COUT + j], s);
    out[(size_t)i * COUT + j] = RELU ? fmaxf(s, 0.0f) : s;
}

// ---------------- GCN propagation: out = D^-1/2 A_hat D^-1/2 h ----------------
// self-loop part (also fully initializes out)
template<int C>
__global__ void prop_self(const float* __restrict__ h, const float* __restrict__ dinv,
                          float* __restrict__ out, int n) {
    int t = blockIdx.x * blockDim.x + threadIdx.x;
    if (t < n * C) {
        int i = t / C;
        float d = dinv[i];
        out[t] = d * d * h[t];
    }
}

// edge scatter part
template<int C>
__global__ void prop_edges(const float* __restrict__ h, const float* __restrict__ dinv,
                           const int* __restrict__ src, const int* __restrict__ dst,
                           float* __restrict__ out, int e) {
    int t = blockIdx.x * blockDim.x + threadIdx.x;
    if (t < e * C) {
        int ed = t / C, c = t - ed * C;
        int s = src[ed], d = dst[ed];
        atomicAdd(&out[d * C + c], dinv[s] * dinv[d] * h[s * C + c]);
    }
}

template<int C>
__global__ void bias_relu(float* h, const float* __restrict__ b, int n) {
    int t = blockIdx.x * blockDim.x + threadIdx.x;
    if (t < n * C) {
        int c = t % C;
        h[t] = fmaxf(h[t] + b[c], 0.0f);
    }
}

// ---------------- a_hat = zs @ zs^T, tiled, write-bound ----------------
__global__ __launch_bounds__(256) void ahat_kernel(const float* __restrict__ zs,
                                                   float* __restrict__ a, int n) {
    int j0 = blockIdx.x * 1024 + threadIdx.x * 4;   // 4 consecutive cols per thread
    int i0 = blockIdx.y * 16;                        // 16 rows per block
    if (j0 + 3 >= n || i0 + 15 >= n) { /* n divisible in practice */ }

    float zj[4][8];
#pragma unroll
    for (int u = 0; u < 4; ++u) {
        float4 lo = *reinterpret_cast<const float4*>(&zs[(size_t)(j0 + u) * 8]);
        float4 hi = *reinterpret_cast<const float4*>(&zs[(size_t)(j0 + u) * 8 + 4]);
        zj[u][0] = lo.x; zj[u][1] = lo.y; zj[u][2] = lo.z; zj[u][3] = lo.w;
        zj[u][4] = hi.x; zj[u][5] = hi.y; zj[u][6] = hi.z; zj[u][7] = hi.w;
    }
    __shared__ float zi[128];   // 16 rows x 8
    if (threadIdx.x < 128) zi[threadIdx.x] = zs[(size_t)i0 * 8 + threadIdx.x];
    __syncthreads();

#pragma unroll
    for (int i = 0; i < 16; ++i) {
        float r[4];
#pragma unroll
        for (int u = 0; u < 4; ++u) {
            float s = 0.0f;
#pragma unroll
            for (int k = 0; k < 8; ++k) s = fmaf(zi[i * 8 + k], zj[u][k], s);
            r[u] = s;
        }
        *reinterpret_cast<float4*>(&a[(size_t)(i0 + i) * n + j0]) =
            make_float4(r[0], r[1], r[2], r[3]);
    }
}

extern "C" void kernel_launch(void* const* d_in, const int* in_sizes, int n_in,
                              void* d_out, int out_size, void* d_ws, size_t ws_size,
                              hipStream_t stream) {
    const float* x  = (const float*)d_in[0];
    const int*   ei = (const int*)d_in[1];
    const float* W1 = (const float*)d_in[2];
    const float* b1 = (const float*)d_in[3];
    const float* W2 = (const float*)d_in[4];
    const float* b2 = (const float*)d_in[5];
    const float* Wa = (const float*)d_in[6];
    const float* ba = (const float*)d_in[7];
    const float* Ws = (const float*)d_in[8];
    const float* bs = (const float*)d_in[9];

    const int n = in_sizes[0] / 128;   // 12288
    const int e = in_sizes[1] / 2;     // 393216
    const int* src = ei;
    const int* dst = ei + e;

    float* xhat = (float*)d_out;                    // [n,128]
    float* ahat = xhat + (size_t)n * 128;           // [n,n]

    // workspace layout (floats)
    float* S    = (float*)d_ws;
    float* dinv = S;                                // n
    float* h1   = S + n;                            // 16n
    float* z1   = h1 + (size_t)16 * n;              // 16n
    float* h2   = z1 + (size_t)16 * n;              // 8n
    float* z    = h2 + (size_t)8 * n;               // 8n
    float* agg  = z  + (size_t)8 * n;               // 8n
    float* zs   = agg + (size_t)8 * n;              // 8n

    auto cdiv = [](long long a, long long b) { return (int)((a + b - 1) / b); };

    // normalization coefficients
    init_deg<<<cdiv(n, TPB), TPB, 0, stream>>>(dinv, n);
    count_deg<<<cdiv(e, TPB), TPB, 0, stream>>>(dst, dinv, e);
    deg_to_dinv<<<cdiv(n, TPB), TPB, 0, stream>>>(dinv, n);

    // layer 1: z1 = relu(prop(x @ W1) + b1)   [n,16]
    mm_kernel<128, 16, false, false><<<cdiv((long long)n * 16, TPB), TPB, 0, stream>>>(x, W1, nullptr, h1, n);
    prop_self<16><<<cdiv((long long)n * 16, TPB), TPB, 0, stream>>>(h1, dinv, z1, n);
    prop_edges<16><<<cdiv((long long)e * 16, TPB), TPB, 0, stream>>>(h1, dinv, src, dst, z1, e);
    bias_relu<16><<<cdiv((long long)n * 16, TPB), TPB, 0, stream>>>(z1, b1, n);

    // layer 2: z = relu(prop(z1 @ W2) + b2)   [n,8]
    mm_kernel<16, 8, false, false><<<cdiv((long long)n * 8, TPB), TPB, 0, stream>>>(z1, W2, nullptr, h2, n);
    prop_self<8><<<cdiv((long long)n * 8, TPB), TPB, 0, stream>>>(h2, dinv, z, n);
    prop_edges<8><<<cdiv((long long)e * 8, TPB), TPB, 0, stream>>>(h2, dinv, src, dst, z, e);
    bias_relu<8><<<cdiv((long long)n * 8, TPB), TPB, 0, stream>>>(z, b2, n);

    // shared aggregation for layers 3/4: agg = prop(z)   [n,8]
    prop_self<8><<<cdiv((long long)n * 8, TPB), TPB, 0, stream>>>(z, dinv, agg, n);
    prop_edges<8><<<cdiv((long long)e * 8, TPB), TPB, 0, stream>>>(z, dinv, src, dst, agg, e);

    // x_hat = agg @ Wa + ba   [n,128]
    mm_kernel<8, 128, true, false><<<cdiv((long long)n * 128, TPB), TPB, 0, stream>>>(agg, Wa, ba, xhat, n);
    // z_struct = relu(agg @ Ws + bs)   [n,8]
    mm_kernel<8, 8, true, true><<<cdiv((long long)n * 8, TPB), TPB, 0, stream>>>(agg, Ws, bs, zs, n);

    // a_hat = zs @ zs^T   [n,n]
    dim3 agrid(cdiv(n, 1024), cdiv(n, 16));
    ahat_kernel<<<agrid, 256, 0, stream>>>(zs, ahat, n);
}

// Round 2
// 242.288 us; speedup vs baseline: 1.0210x; 1.0210x over previous
//
#include <hip/hip_runtime.h>

#define TPB 256

// ---------------- CSR build: histogram -> scan -> scatter ----------------
__global__ void zero_cnt(int* cnt, int n) {
    int i = blockIdx.x * blockDim.x + threadIdx.x;
    if (i < n) cnt[i] = 0;
}

__global__ void hist_dst(const int* __restrict__ dst, int* cnt, int e) {
    int i = blockIdx.x * blockDim.x + threadIdx.x;
    if (i < e) atomicAdd(&cnt[dst[i]], 1);
}

// single block of 256; each thread owns PER contiguous bins (two passes over cnt)
__global__ void scan_kernel(const int* __restrict__ cnt, int* __restrict__ off,
                            int* __restrict__ cursor, float* __restrict__ dinv, int n) {
    const int PER = (n + 255) / 256;
    int tid = threadIdx.x;
    int base = tid * PER;
    int sum = 0;
    for (int k = 0; k < PER; ++k) {
        int i = base + k;
        if (i < n) sum += cnt[i];
    }
    int lane = tid & 63, wid = tid >> 6;
    int inc = sum;
    for (int s = 1; s < 64; s <<= 1) {
        int t = __shfl_up(inc, s);
        if (lane >= s) inc += t;
    }
    __shared__ int wsum[4];
    if (lane == 63) wsum[wid] = inc;
    __syncthreads();
    int woff = 0;
    for (int w = 0; w < wid; ++w) woff += wsum[w];
    int run = woff + inc - sum;   // exclusive prefix for this thread's chunk
    for (int k = 0; k < PER; ++k) {
        int i = base + k;
        if (i < n) {
            int v = cnt[i];
            off[i] = run;
            cursor[i] = run;
            dinv[i] = rsqrtf((float)(v + 1));   // +1 self loop
            run += v;
        }
    }
}

__global__ void scatter_csr(const int* __restrict__ src, const int* __restrict__ dst,
                            int* cursor, int* __restrict__ csr, int e) {
    int t = blockIdx.x * blockDim.x + threadIdx.x;
    if (t < e) {
        int d = dst[t];
        int pos = atomicAdd(&cursor[d], 1);
        csr[pos] = src[t];
    }
}

// ---------------- dense matmul: out[n,COUT] = in[n,CIN] @ W ----------------
template<int CIN, int COUT>
__global__ void mm_kernel(const float* __restrict__ in, const float* __restrict__ W,
                          float* __restrict__ out, int n) {
    __shared__ float Wl[CIN * COUT];
    for (int t = threadIdx.x; t < CIN * COUT; t += blockDim.x) Wl[t] = W[t];
    __syncthreads();
    int t = blockIdx.x * blockDim.x + threadIdx.x;
    int i = t / COUT, j = t - i * COUT;
    if (i >= n) return;
    float s = 0.0f;
#pragma unroll
    for (int k = 0; k < CIN; ++k) s = fmaf(in[(size_t)i * CIN + k], Wl[k * COUT + j], s);
    out[(size_t)i * COUT + j] = s;
}

// ---------------- layer1 gather: z1 = relu(P(h1)+b1); h2 = z1@W2 ----------------
// one wave per node; C=16, 4 edges in parallel
__global__ __launch_bounds__(256) void gather_l1(
        const float* __restrict__ h1, const float* __restrict__ dinv,
        const int* __restrict__ off, const int* __restrict__ cnt,
        const int* __restrict__ csr, const float* __restrict__ b1,
        const float* __restrict__ W2, float* __restrict__ h2, int n) {
    int wave = (blockIdx.x * blockDim.x + threadIdx.x) >> 6;
    int lane = threadIdx.x & 63;
    if (wave >= n) return;
    const int i = wave;
    const int c = lane & 15;
    const int eg = lane >> 4;                 // 0..3
    int start = off[i], deg = cnt[i];
    float acc = 0.0f;
    for (int eb = eg; eb < deg; eb += 4) {
        int s = csr[start + eb];
        acc += dinv[s] * h1[(size_t)s * 16 + c];
    }
    acc += __shfl_xor(acc, 16);
    acc += __shfl_xor(acc, 32);
    float di = dinv[i];
    float z1c = di * (acc + di * h1[(size_t)i * 16 + c]) + b1[c];
    z1c = fmaxf(z1c, 0.0f);                   // lanes 0..15 hold z1[c]; dup in eg groups
    // h2[j] = sum_k z1[k]*W2[k*8+j]
    const int j = lane & 7;
    float hj = 0.0f;
#pragma unroll
    for (int k = 0; k < 16; ++k) {
        float v = __shfl(z1c, k);             // z1 channel k
        hj = fmaf(v, W2[k * 8 + j], hj);
    }
    if (lane < 8) h2[(size_t)i * 8 + lane] = hj;
}

// ---------------- layer2 gather: z = relu(P(h2)+b2) ----------------
__global__ __launch_bounds__(256) void gather_l2(
        const float* __restrict__ h2, const float* __restrict__ dinv,
        const int* __restrict__ off, const int* __restrict__ cnt,
        const int* __restrict__ csr, const float* __restrict__ b2,
        float* __restrict__ z, int n) {
    int wave = (blockIdx.x * blockDim.x + threadIdx.x) >> 6;
    int lane = threadIdx.x & 63;
    if (wave >= n) return;
    const int i = wave;
    const int c = lane & 7;
    const int eg = lane >> 3;                 // 0..7
    int start = off[i], deg = cnt[i];
    float acc = 0.0f;
    for (int eb = eg; eb < deg; eb += 8) {
        int s = csr[start + eb];
        acc += dinv[s] * h2[(size_t)s * 8 + c];
    }
    acc += __shfl_xor(acc, 8);
    acc += __shfl_xor(acc, 16);
    acc += __shfl_xor(acc, 32);
    float di = dinv[i];
    float zc = fmaxf(di * (acc + di * h2[(size_t)i * 8 + c]) + b2[c], 0.0f);
    if (lane < 8) z[(size_t)i * 8 + lane] = zc;
}

// ---------------- layer3/4 fused: agg = P(z); xhat = agg@Wa+ba; zs = relu(agg@Ws+bs) ----------------
__global__ __launch_bounds__(256) void gather_l34(
        const float* __restrict__ z, const float* __restrict__ dinv,
        const int* __restrict__ off, const int* __restrict__ cnt,
        const int* __restrict__ csr,
        const float* __restrict__ Wa, const float* __restrict__ ba,
        const float* __restrict__ Ws, const float* __restrict__ bs,
        float* __restrict__ xhat, float* __restrict__ zs, int n) {
    int wave = (blockIdx.x * blockDim.x + threadIdx.x) >> 6;
    int lane = threadIdx.x & 63;
    if (wave >= n) return;
    const int i = wave;
    const int c = lane & 7;
    const int eg = lane >> 3;
    int start = off[i], deg = cnt[i];
    float acc = 0.0f;
    for (int eb = eg; eb < deg; eb += 8) {
        int s = csr[start + eb];
        acc += dinv[s] * z[(size_t)s * 8 + c];
    }
    acc += __shfl_xor(acc, 8);
    acc += __shfl_xor(acc, 16);
    acc += __shfl_xor(acc, 32);
    float di = dinv[i];
    float agg = di * (acc + di * z[(size_t)i * 8 + c]);   // all lanes: agg for channel c
    float o0 = ba[lane], o1 = ba[lane + 64];
    float zsj = bs[c];
#pragma unroll
    for (int k = 0; k < 8; ++k) {
        float a = __shfl(agg, k);             // agg channel k (from lane k)
        o0 = fmaf(a, Wa[k * 128 + lane], o0);
        o1 = fmaf(a, Wa[k * 128 + lane + 64], o1);
        zsj = fmaf(a, Ws[k * 8 + c], zsj);
    }
    xhat[(size_t)i * 128 + lane] = o0;
    xhat[(size_t)i * 128 + lane + 64] = o1;
    if (lane < 8) zs[(size_t)i * 8 + lane] = fmaxf(zsj, 0.0f);
}

// ---------------- a_hat = zs @ zs^T (write-bound) ----------------
__global__ __launch_bounds__(256) void ahat_kernel(const float* __restrict__ zs,
                                                   float* __restrict__ a, int n) {
    int j0 = blockIdx.x * 1024 + threadIdx.x * 4;
    int i0 = blockIdx.y * 16;
    float zj[4][8];
#pragma unroll
    for (int u = 0; u < 4; ++u) {
        float4 lo = *reinterpret_cast<const float4*>(&zs[(size_t)(j0 + u) * 8]);
        float4 hi = *reinterpret_cast<const float4*>(&zs[(size_t)(j0 + u) * 8 + 4]);
        zj[u][0] = lo.x; zj[u][1] = lo.y; zj[u][2] = lo.z; zj[u][3] = lo.w;
        zj[u][4] = hi.x; zj[u][5] = hi.y; zj[u][6] = hi.z; zj[u][7] = hi.w;
    }
    __shared__ float zi[128];
    if (threadIdx.x < 128) zi[threadIdx.x] = zs[(size_t)i0 * 8 + threadIdx.x];
    __syncthreads();
#pragma unroll
    for (int i = 0; i < 16; ++i) {
        float r[4];
#pragma unroll
        for (int u = 0; u < 4; ++u) {
            float s = 0.0f;
#pragma unroll
            for (int k = 0; k < 8; ++k) s = fmaf(zi[i * 8 + k], zj[u][k], s);
            r[u] = s;
        }
        *reinterpret_cast<float4*>(&a[(size_t)(i0 + i) * n + j0]) =
            make_float4(r[0], r[1], r[2], r[3]);
    }
}

extern "C" void kernel_launch(void* const* d_in, const int* in_sizes, int n_in,
                              void* d_out, int out_size, void* d_ws, size_t ws_size,
                              hipStream_t stream) {
    const float* x  = (const float*)d_in[0];
    const int*   ei = (const int*)d_in[1];
    const float* W1 = (const float*)d_in[2];
    const float* b1 = (const float*)d_in[3];
    const float* W2 = (const float*)d_in[4];
    const float* b2 = (const float*)d_in[5];
    const float* Wa = (const float*)d_in[6];
    const float* ba = (const float*)d_in[7];
    const float* Ws = (const float*)d_in[8];
    const float* bs = (const float*)d_in[9];

    const int n = in_sizes[0] / 128;   // 12288
    const int e = in_sizes[1] / 2;     // 393216
    const int* src = ei;
    const int* dst = ei + e;

    float* xhat = (float*)d_out;                    // [n,128]
    float* ahat = xhat + (size_t)n * 128;           // [n,n]

    // workspace layout
    int*   cnt    = (int*)d_ws;                     // n
    int*   off    = cnt + n;                        // n
    int*   cursor = off + n;                        // n
    int*   csr    = cursor + n;                     // e
    float* dinv   = (float*)(csr + e);              // n
    float* h1     = dinv + n;                       // 16n
    float* h2     = h1 + (size_t)16 * n;            // 8n
    float* z      = h2 + (size_t)8 * n;             // 8n
    float* zs     = z  + (size_t)8 * n;             // 8n

    auto cdiv = [](long long a, long long b) { return (int)((a + b - 1) / b); };

    // CSR build + norm coefficients
    zero_cnt<<<cdiv(n, TPB), TPB, 0, stream>>>(cnt, n);
    hist_dst<<<cdiv(e, TPB), TPB, 0, stream>>>(dst, cnt, e);
    scan_kernel<<<1, 256, 0, stream>>>(cnt, off, cursor, dinv, n);
    scatter_csr<<<cdiv(e, TPB), TPB, 0, stream>>>(src, dst, cursor, csr, e);

    // h1 = x @ W1   [n,16]
    mm_kernel<128, 16><<<cdiv((long long)n * 16, TPB), TPB, 0, stream>>>(x, W1, h1, n);

    // z1 = relu(P h1 + b1); h2 = z1 @ W2   [n,8]  (fused)
    gather_l1<<<cdiv((long long)n * 64, TPB), TPB, 0, stream>>>(h1, dinv, off, cnt, csr, b1, W2, h2, n);

    // z = relu(P h2 + b2)   [n,8]
    gather_l2<<<cdiv((long long)n * 64, TPB), TPB, 0, stream>>>(h2, dinv, off, cnt, csr, b2, z, n);

    // agg = P z; xhat = agg@Wa+ba; zs = relu(agg@Ws+bs)  (fused)
    gather_l34<<<cdiv((long long)n * 64, TPB), TPB, 0, stream>>>(z, dinv, off, cnt, csr,
                                                                 Wa, ba, Ws, bs, xhat, zs, n);

    // a_hat = zs @ zs^T
    dim3 agrid(cdiv(n, 1024), cdiv(n, 16));
    ahat_kernel<<<agrid, 256, 0, stream>>>(zs, ahat, n);
}

// Round 4
// 239.029 us; speedup vs baseline: 1.0350x; 1.0136x over previous
//
#include <hip/hip_runtime.h>

#define TPB 256

typedef float f32x4 __attribute__((ext_vector_type(4)));

// ---------------- CSR build: histogram -> scan -> scatter ----------------
__global__ void zero_cnt(int* cnt, int n) {
    int i = blockIdx.x * blockDim.x + threadIdx.x;
    if (i < n) cnt[i] = 0;
}

__global__ void hist_dst(const int* __restrict__ dst, int* cnt, int e) {
    int i = blockIdx.x * blockDim.x + threadIdx.x;
    if (i < e) atomicAdd(&cnt[dst[i]], 1);
}

// single block of 256; each thread owns PER contiguous bins (two passes over cnt)
__global__ void scan_kernel(const int* __restrict__ cnt, int* __restrict__ off,
                            int* __restrict__ cursor, float* __restrict__ dinv, int n) {
    const int PER = (n + 255) / 256;
    int tid = threadIdx.x;
    int base = tid * PER;
    int sum = 0;
    for (int k = 0; k < PER; ++k) {
        int i = base + k;
        if (i < n) sum += cnt[i];
    }
    int lane = tid & 63, wid = tid >> 6;
    int inc = sum;
    for (int s = 1; s < 64; s <<= 1) {
        int t = __shfl_up(inc, s);
        if (lane >= s) inc += t;
    }
    __shared__ int wsum[4];
    if (lane == 63) wsum[wid] = inc;
    __syncthreads();
    int woff = 0;
    for (int w = 0; w < wid; ++w) woff += wsum[w];
    int run = woff + inc - sum;   // exclusive prefix for this thread's chunk
    for (int k = 0; k < PER; ++k) {
        int i = base + k;
        if (i < n) {
            int v = cnt[i];
            off[i] = run;
            cursor[i] = run;
            dinv[i] = rsqrtf((float)(v + 1));   // +1 self loop
            run += v;
        }
    }
}

__global__ void scatter_csr(const int* __restrict__ src, const int* __restrict__ dst,
                            int* cursor, int* __restrict__ csr, int e) {
    int t = blockIdx.x * blockDim.x + threadIdx.x;
    if (t < e) {
        int d = dst[t];
        int pos = atomicAdd(&cursor[d], 1);
        csr[pos] = src[t];
    }
}

// ---------------- dense matmul: out[n,COUT] = in[n,CIN] @ W ----------------
template<int CIN, int COUT>
__global__ void mm_kernel(const float* __restrict__ in, const float* __restrict__ W,
                          float* __restrict__ out, int n) {
    __shared__ float Wl[CIN * COUT];
    for (int t = threadIdx.x; t < CIN * COUT; t += blockDim.x) Wl[t] = W[t];
    __syncthreads();
    int t = blockIdx.x * blockDim.x + threadIdx.x;
    int i = t / COUT, j = t - i * COUT;
    if (i >= n) return;
    float s = 0.0f;
#pragma unroll
    for (int k = 0; k < CIN; ++k) s = fmaf(in[(size_t)i * CIN + k], Wl[k * COUT + j], s);
    out[(size_t)i * COUT + j] = s;
}

// ---------------- layer1 gather: z1 = relu(P(h1)+b1); h2 = z1@W2 ----------------
__global__ __launch_bounds__(256) void gather_l1(
        const float* __restrict__ h1, const float* __restrict__ dinv,
        const int* __restrict__ off, const int* __restrict__ cnt,
        const int* __restrict__ csr, const float* __restrict__ b1,
        const float* __restrict__ W2, float* __restrict__ h2, int n) {
    int wave = (blockIdx.x * blockDim.x + threadIdx.x) >> 6;
    int lane = threadIdx.x & 63;
    if (wave >= n) return;
    const int i = wave;
    const int c = lane & 15;
    const int eg = lane >> 4;                 // 0..3
    int start = off[i], deg = cnt[i];
    float acc = 0.0f;
    for (int eb = eg; eb < deg; eb += 4) {
        int s = csr[start + eb];
        acc += dinv[s] * h1[(size_t)s * 16 + c];
    }
    acc += __shfl_xor(acc, 16);
    acc += __shfl_xor(acc, 32);
    float di = dinv[i];
    float z1c = di * (acc + di * h1[(size_t)i * 16 + c]) + b1[c];
    z1c = fmaxf(z1c, 0.0f);
    const int j = lane & 7;
    float hj = 0.0f;
#pragma unroll
    for (int k = 0; k < 16; ++k) {
        float v = __shfl(z1c, k);
        hj = fmaf(v, W2[k * 8 + j], hj);
    }
    if (lane < 8) h2[(size_t)i * 8 + lane] = hj;
}

// ---------------- layer2 gather: z = relu(P(h2)+b2) ----------------
__global__ __launch_bounds__(256) void gather_l2(
        const float* __restrict__ h2, const float* __restrict__ dinv,
        const int* __restrict__ off, const int* __restrict__ cnt,
        const int* __restrict__ csr, const float* __restrict__ b2,
        float* __restrict__ z, int n) {
    int wave = (blockIdx.x * blockDim.x + threadIdx.x) >> 6;
    int lane = threadIdx.x & 63;
    if (wave >= n) return;
    const int i = wave;
    const int c = lane & 7;
    const int eg = lane >> 3;                 // 0..7
    int start = off[i], deg = cnt[i];
    float acc = 0.0f;
    for (int eb = eg; eb < deg; eb += 8) {
        int s = csr[start + eb];
        acc += dinv[s] * h2[(size_t)s * 8 + c];
    }
    acc += __shfl_xor(acc, 8);
    acc += __shfl_xor(acc, 16);
    acc += __shfl_xor(acc, 32);
    float di = dinv[i];
    float zc = fmaxf(di * (acc + di * h2[(size_t)i * 8 + c]) + b2[c], 0.0f);
    if (lane < 8) z[(size_t)i * 8 + lane] = zc;
}

// ---------------- layer3/4 fused: agg = P(z); xhat = agg@Wa+ba; zs = relu(agg@Ws+bs) ----------------
__global__ __launch_bounds__(256) void gather_l34(
        const float* __restrict__ z, const float* __restrict__ dinv,
        const int* __restrict__ off, const int* __restrict__ cnt,
        const int* __restrict__ csr,
        const float* __restrict__ Wa, const float* __restrict__ ba,
        const float* __restrict__ Ws, const float* __restrict__ bs,
        float* __restrict__ xhat, float* __restrict__ zs, int n) {
    int wave = (blockIdx.x * blockDim.x + threadIdx.x) >> 6;
    int lane = threadIdx.x & 63;
    if (wave >= n) return;
    const int i = wave;
    const int c = lane & 7;
    const int eg = lane >> 3;
    int start = off[i], deg = cnt[i];
    float acc = 0.0f;
    for (int eb = eg; eb < deg; eb += 8) {
        int s = csr[start + eb];
        acc += dinv[s] * z[(size_t)s * 8 + c];
    }
    acc += __shfl_xor(acc, 8);
    acc += __shfl_xor(acc, 16);
    acc += __shfl_xor(acc, 32);
    float di = dinv[i];
    float agg = di * (acc + di * z[(size_t)i * 8 + c]);
    float o0 = ba[lane], o1 = ba[lane + 64];
    float zsj = bs[c];
#pragma unroll
    for (int k = 0; k < 8; ++k) {
        float a = __shfl(agg, k);
        o0 = fmaf(a, Wa[k * 128 + lane], o0);
        o1 = fmaf(a, Wa[k * 128 + lane + 64], o1);
        zsj = fmaf(a, Ws[k * 8 + c], zsj);
    }
    __builtin_nontemporal_store(o0, &xhat[(size_t)i * 128 + lane]);
    __builtin_nontemporal_store(o1, &xhat[(size_t)i * 128 + lane + 64]);
    if (lane < 8) zs[(size_t)i * 8 + lane] = fmaxf(zsj, 0.0f);
}

// ---------------- a_hat = zs @ zs^T (write-bound, non-temporal stores) ----------------
__global__ __launch_bounds__(256) void ahat_kernel(const float* __restrict__ zs,
                                                   float* __restrict__ a, int n) {
    int j0 = blockIdx.x * 1024 + threadIdx.x * 4;
    int i0 = blockIdx.y * 16;
    float zj[4][8];
#pragma unroll
    for (int u = 0; u < 4; ++u) {
        float4 lo = *reinterpret_cast<const float4*>(&zs[(size_t)(j0 + u) * 8]);
        float4 hi = *reinterpret_cast<const float4*>(&zs[(size_t)(j0 + u) * 8 + 4]);
        zj[u][0] = lo.x; zj[u][1] = lo.y; zj[u][2] = lo.z; zj[u][3] = lo.w;
        zj[u][4] = hi.x; zj[u][5] = hi.y; zj[u][6] = hi.z; zj[u][7] = hi.w;
    }
    __shared__ float zi[128];
    if (threadIdx.x < 128) zi[threadIdx.x] = zs[(size_t)i0 * 8 + threadIdx.x];
    __syncthreads();
#pragma unroll
    for (int i = 0; i < 16; ++i) {
        float r[4];
#pragma unroll
        for (int u = 0; u < 4; ++u) {
            float s = 0.0f;
#pragma unroll
            for (int k = 0; k < 8; ++k) s = fmaf(zi[i * 8 + k], zj[u][k], s);
            r[u] = s;
        }
        f32x4 v = { r[0], r[1], r[2], r[3] };
        __builtin_nontemporal_store(v, reinterpret_cast<f32x4*>(&a[(size_t)(i0 + i) * n + j0]));
    }
}

extern "C" void kernel_launch(void* const* d_in, const int* in_sizes, int n_in,
                              void* d_out, int out_size, void* d_ws, size_t ws_size,
                              hipStream_t stream) {
    const float* x  = (const float*)d_in[0];
    const int*   ei = (const int*)d_in[1];
    const float* W1 = (const float*)d_in[2];
    const float* b1 = (const float*)d_in[3];
    const float* W2 = (const float*)d_in[4];
    const float* b2 = (const float*)d_in[5];
    const float* Wa = (const float*)d_in[6];
    const float* ba = (const float*)d_in[7];
    const float* Ws = (const float*)d_in[8];
    const float* bs = (const float*)d_in[9];

    const int n = in_sizes[0] / 128;   // 12288
    const int e = in_sizes[1] / 2;     // 393216
    const int* src = ei;
    const int* dst = ei + e;

    float* xhat = (float*)d_out;                    // [n,128]
    float* ahat = xhat + (size_t)n * 128;           // [n,n]

    // workspace layout
    int*   cnt    = (int*)d_ws;                     // n
    int*   off    = cnt + n;                        // n
    int*   cursor = off + n;                        // n
    int*   csr    = cursor + n;                     // e
    float* dinv   = (float*)(csr + e);              // n
    float* h1     = dinv + n;                       // 16n
    float* h2     = h1 + (size_t)16 * n;            // 8n
    float* z      = h2 + (size_t)8 * n;             // 8n
    float* zs     = z  + (size_t)8 * n;             // 8n

    auto cdiv = [](long long a, long long b) { return (int)((a + b - 1) / b); };

    // CSR build + norm coefficients
    zero_cnt<<<cdiv(n, TPB), TPB, 0, stream>>>(cnt, n);
    hist_dst<<<cdiv(e, TPB), TPB, 0, stream>>>(dst, cnt, e);
    scan_kernel<<<1, 256, 0, stream>>>(cnt, off, cursor, dinv, n);
    scatter_csr<<<cdiv(e, TPB), TPB, 0, stream>>>(src, dst, cursor, csr, e);

    // h1 = x @ W1   [n,16]
    mm_kernel<128, 16><<<cdiv((long long)n * 16, TPB), TPB, 0, stream>>>(x, W1, h1, n);

    // z1 = relu(P h1 + b1); h2 = z1 @ W2   [n,8]  (fused)
    gather_l1<<<cdiv((long long)n * 64, TPB), TPB, 0, stream>>>(h1, dinv, off, cnt, csr, b1, W2, h2, n);

    // z = relu(P h2 + b2)   [n,8]
    gather_l2<<<cdiv((long long)n * 64, TPB), TPB, 0, stream>>>(h2, dinv, off, cnt, csr, b2, z, n);

    // agg = P z; xhat = agg@Wa+ba; zs = relu(agg@Ws+bs)  (fused)
    gather_l34<<<cdiv((long long)n * 64, TPB), TPB, 0, stream>>>(z, dinv, off, cnt, csr,
                                                                 Wa, ba, Ws, bs, xhat, zs, n);

    // a_hat = zs @ zs^T
    dim3 agrid(cdiv(n, 1024), cdiv(n, 16));
    ahat_kernel<<<agrid, 256, 0, stream>>>(zs, ahat, n);
}